// Round 3
// baseline (287.920 us; speedup 1.0000x reference)
//
#include <hip/hip_runtime.h>

#define SEQ   16384
#define NB    4
#define NROWS 65536
#define NC    512           // chunks per (dir,b)
#define CL    32            // chunk length

typedef short bf16x8 __attribute__((ext_vector_type(8)));
typedef float f32x4  __attribute__((ext_vector_type(4)));
typedef float f32x2  __attribute__((ext_vector_type(2)));

__device__ inline float bf2f(ushort u) {
    unsigned int t = ((unsigned int)u) << 16;
    float f; __builtin_memcpy(&f, &t, 4); return f;
}
__device__ inline ushort f2bf(float f) {
    unsigned int b; __builtin_memcpy(&b, &f, 4);
    unsigned int r = (b + 0x7FFFu + ((b >> 16) & 1u)) >> 16;
    return (ushort)r;
}

// ---------------- weight prep ----------------
// BTv [512 n][256 k] (n<256 dir0, n>=256 dir1), WoT [256 n][512 k],
// WgT [2][16 s][256 k], bias_v [512]
__global__ __launch_bounds__(256) void prep_weights(
    const float* __restrict__ Wf, const float* __restrict__ Wb,
    const float* __restrict__ Wo, const float* __restrict__ Wgf,
    const float* __restrict__ Wgb, const float* __restrict__ bfp,
    const float* __restrict__ bbp,
    ushort* __restrict__ BTv, ushort* __restrict__ WoT,
    ushort* __restrict__ WgT, float* __restrict__ bias_v)
{
    int idx = blockIdx.x * 256 + threadIdx.x;
    if (idx < 131072) {                 // BTv
        int dir = idx >> 16, j = idx & 65535, n = j >> 8, k = j & 255;
        const float* W = dir ? Wb : Wf;
        BTv[idx] = f2bf(W[k * 512 + 256 + n]);
    } else if (idx < 262144) {          // WoT
        int j = idx - 131072; int n = j >> 9, k = j & 511;
        WoT[j] = f2bf(Wo[k * 256 + n]);
    } else if (idx < 270336) {          // WgT
        int j = idx - 262144; int dir = j >> 12, jj = j & 4095, s = jj >> 8, k = jj & 255;
        WgT[j] = f2bf((dir ? Wgb : Wgf)[k * 16 + s]);
    } else if (idx < 270848) {          // bias_v
        int j = idx - 270336; int dir = j >> 8, n = j & 255;
        bias_v[j] = (dir ? bbp : bfp)[256 + n];
    }
}

// ---------------- value GEMM: 64x512 tile (both dirs), fp32 A converted in staging
__global__ __launch_bounds__(256) void gemm_value(
    const float* __restrict__ x, const ushort* __restrict__ BTv,
    const float* __restrict__ bias_v, ushort* __restrict__ value)
{
    __shared__ ushort Al[64 * 40];
    __shared__ ushort Bl[512 * 40];
    const int tid = threadIdx.x;
    const int m0 = blockIdx.x * 64;
    const int w = tid >> 6, l = tid & 63, l15 = l & 15, lk = (l >> 4) * 8;
    f32x4 acc[4][8] = {};

    for (int kk = 0; kk < 256; kk += 32) {
        {
            int r = tid >> 2, c = (tid & 3) * 8;
            const float* xp = x + (size_t)(m0 + r) * 256 + kk + c;
            float4 a = *(const float4*)xp;
            float4 b = *(const float4*)(xp + 4);
            ushort u[8];
            u[0] = f2bf(a.x); u[1] = f2bf(a.y); u[2] = f2bf(a.z); u[3] = f2bf(a.w);
            u[4] = f2bf(b.x); u[5] = f2bf(b.y); u[6] = f2bf(b.z); u[7] = f2bf(b.w);
            *(uint4*)&Al[r * 40 + c] = *(uint4*)u;
        }
        #pragma unroll
        for (int i = 0; i < 8; ++i) {
            int idx = tid + i * 256; int r = idx >> 2, c = idx & 3;
            *(uint4*)&Bl[r * 40 + c * 8] = *(const uint4*)(BTv + (size_t)r * 256 + kk + c * 8);
        }
        __syncthreads();
        bf16x8 af[4], bfr[8];
        #pragma unroll
        for (int m = 0; m < 4; ++m) af[m] = *(const bf16x8*)&Al[(m * 16 + l15) * 40 + lk];
        #pragma unroll
        for (int n = 0; n < 8; ++n) bfr[n] = *(const bf16x8*)&Bl[(w * 128 + n * 16 + l15) * 40 + lk];
        #pragma unroll
        for (int m = 0; m < 4; ++m)
            #pragma unroll
            for (int n = 0; n < 8; ++n)
                acc[m][n] = __builtin_amdgcn_mfma_f32_16x16x32_bf16(af[m], bfr[n], acc[m][n], 0, 0, 0);
        __syncthreads();
    }
    const int rbase = (l >> 4) * 4;
    #pragma unroll
    for (int m = 0; m < 4; ++m)
        #pragma unroll
        for (int n = 0; n < 8; ++n) {
            int col = w * 128 + n * 16 + l15;
            float bv = bias_v[col];
            #pragma unroll
            for (int r = 0; r < 4; ++r) {
                int row = m0 + m * 16 + rbase + r;
                value[(size_t)row * 512 + col] = f2bf(acc[m][n][r] + bv);
            }
        }
}

// ---------------- gate via MFMA: 64 rows x 16 s, grid.y = dir ----------------
__global__ __launch_bounds__(256) void gate_mfma(
    const ushort* __restrict__ value, const ushort* __restrict__ WgT,
    const float* __restrict__ bgf, const float* __restrict__ bgb,
    float* __restrict__ gw)
{
    __shared__ ushort Av[64 * 264];
    const int tid = threadIdx.x;
    const int r0 = blockIdx.x * 64, dir = blockIdx.y;
    #pragma unroll
    for (int i = 0; i < 8; ++i) {
        int idx = tid + i * 256; int r = idx >> 5, c = idx & 31;
        *(uint4*)&Av[r * 264 + c * 8] =
            *(const uint4*)(value + (size_t)(r0 + r) * 512 + dir * 256 + c * 8);
    }
    __syncthreads();
    const int w = tid >> 6, l = tid & 63, l15 = l & 15, lk = (l >> 4) * 8;
    const ushort* Wg = WgT + dir * 4096;
    f32x4 acc = {};
    #pragma unroll
    for (int kk = 0; kk < 256; kk += 32) {
        bf16x8 af = *(const bf16x8*)&Av[(w * 16 + l15) * 264 + kk + lk];
        bf16x8 bf = *(const bf16x8*)(Wg + l15 * 256 + kk + lk);
        acc = __builtin_amdgcn_mfma_f32_16x16x32_bf16(af, bf, acc, 0, 0, 0);
    }
    const float* bg = dir ? bgb : bgf;
    float bgs = bg[l15];
    const int rbase = (l >> 4) * 4;
    #pragma unroll
    for (int r = 0; r < 4; ++r) {
        int gr = r0 + w * 16 + rbase + r;
        int b = gr >> 14, t = gr & 16383;
        float sv = 1.f / (1.f + __expf(-(acc[r] + bgs)));
        gw[((size_t)(dir * NB + b) * SEQ + t) * 16 + l15] = sv;
    }
}

// ---------------- pass A: local chunk-final states + decay products ----------------
__global__ __launch_bounds__(128) void pass_a(
    const ushort* __restrict__ value, const float* __restrict__ gw,
    float* __restrict__ L, float* __restrict__ P)
{
    const int chunk = blockIdx.x, b = blockIdx.y, dir = blockIdx.z;
    const int tid = threadIdx.x;
    __shared__ float gs[CL * 16];
    const float* gwd = gw + ((size_t)(dir * NB + b) * SEQ + chunk * CL) * 16;
    ((float4*)gs)[tid] = ((const float4*)gwd)[tid];
    __syncthreads();
    const ushort* vb = value + ((size_t)b * SEQ + chunk * CL) * 512 + dir * 256 + tid * 2;
    f32x2 c[16] = {};
    for (int i = 0; i < CL; ++i) {
        int row = dir ? (CL - 1 - i) : i;
        uint vv = *(const uint*)(vb + (size_t)row * 512);
        f32x2 v; v.x = bf2f((ushort)(vv & 0xffffu)); v.y = bf2f((ushort)(vv >> 16));
        float g[16];
        #pragma unroll
        for (int q = 0; q < 4; ++q)
            *(float4*)&g[q * 4] = *(const float4*)&gs[row * 16 + q * 4];
        #pragma unroll
        for (int s = 0; s < 16; ++s) {
            f32x2 gg; gg.x = g[s]; gg.y = g[s];
            c[s] = v + gg * (c[s] - v);
        }
    }
    float* Lp = L + ((size_t)(dir * NB + b) * NC + chunk) * 4096 + tid * 2;
    #pragma unroll
    for (int s = 0; s < 16; ++s)
        *(f32x2*)(Lp + s * 256) = c[s];
    if (tid < 16) {
        float p = 1.f;
        for (int t = 0; t < CL; ++t) p *= gs[t * 16 + tid];
        P[((size_t)(dir * NB + b) * NC + chunk) * 16 + tid] = p;
    }
}

// ---------------- pass B: chunk-level recurrence (L -> entry states, in place) ----
__global__ __launch_bounds__(128) void chunk_scan(
    float* __restrict__ L, const float* __restrict__ P)
{
    const int bid = blockIdx.x;          // 256 = 2 dir * 4 b * 16 s * 2 dhalf
    const int dir = bid >> 7, b = (bid >> 5) & 3, s = (bid >> 1) & 15, dh = bid & 1;
    const int d = dh * 128 + threadIdx.x;
    const size_t cb = (size_t)(dir * NB + b) * NC;
    float e = 0.f;
    #pragma unroll 4
    for (int i = 0; i < NC; ++i) {
        int k = dir ? (NC - 1 - i) : i;
        size_t off = (cb + k) * 4096 + s * 256 + d;
        float l = L[off];
        float pv = P[(cb + k) * 16 + s];
        L[off] = e;
        e = pv * e + l;
    }
}

// ---------------- pass C: re-run local scan with entry state, write in place ------
__global__ __launch_bounds__(128) void pass_c(
    ushort* __restrict__ value, const float* __restrict__ gw,
    const float* __restrict__ L, const float* __restrict__ A_f,
    const float* __restrict__ A_b)
{
    const int chunk = blockIdx.x, b = blockIdx.y, dir = blockIdx.z;
    const int tid = threadIdx.x;
    __shared__ float gs[CL * 16];
    const float* gwd = gw + ((size_t)(dir * NB + b) * SEQ + chunk * CL) * 16;
    ((float4*)gs)[tid] = ((const float4*)gwd)[tid];
    __syncthreads();
    ushort* vb = value + ((size_t)b * SEQ + chunk * CL) * 512 + dir * 256 + tid * 2;
    const float* Ad = dir ? A_b : A_f;
    const float* Lp = L + ((size_t)(dir * NB + b) * NC + chunk) * 4096 + tid * 2;
    f32x2 a[16], c[16];
    #pragma unroll
    for (int s = 0; s < 16; ++s) {
        a[s] = *(const f32x2*)(Ad + s * 256 + tid * 2);
        c[s] = *(const f32x2*)(Lp + s * 256);
    }
    for (int i = 0; i < CL; ++i) {
        int row = dir ? (CL - 1 - i) : i;
        uint vv = *(const uint*)(vb + (size_t)row * 512);
        f32x2 v; v.x = bf2f((ushort)(vv & 0xffffu)); v.y = bf2f((ushort)(vv >> 16));
        float g[16];
        #pragma unroll
        for (int q = 0; q < 4; ++q)
            *(float4*)&g[q * 4] = *(const float4*)&gs[row * 16 + q * 4];
        f32x2 o = {0.f, 0.f};
        #pragma unroll
        for (int s = 0; s < 16; ++s) {
            f32x2 gg; gg.x = g[s]; gg.y = g[s];
            c[s] = v + gg * (c[s] - v);
            o += a[s] * (gg * c[s]);
        }
        uint outv = (uint)f2bf(o.x) | ((uint)f2bf(o.y) << 16);
        *(uint*)(vb + (size_t)row * 512) = outv;
    }
}

// ---------------- out GEMM (K=512) with fused LayerNorm epilogue ----------------
__global__ __launch_bounds__(256) void gemm_out_ln(
    const ushort* __restrict__ A, const ushort* __restrict__ BT,
    const float* __restrict__ b_out, const float* __restrict__ ln_g,
    const float* __restrict__ ln_b, float* __restrict__ out)
{
    __shared__ ushort Al[64 * 40];
    __shared__ ushort Bl[256 * 40];
    __shared__ float red[2][4][64];
    const int tid = threadIdx.x;
    const int m0 = blockIdx.x * 64;
    const int w = tid >> 6, l = tid & 63, l15 = l & 15, lk = (l >> 4) * 8;
    f32x4 acc[4][4] = {};

    for (int kk = 0; kk < 512; kk += 32) {
        {
            int r = tid >> 2, c = tid & 3;
            *(uint4*)&Al[r * 40 + c * 8] = *(const uint4*)(A + (size_t)(m0 + r) * 512 + kk + c * 8);
        }
        #pragma unroll
        for (int i = 0; i < 4; ++i) {
            int idx = tid + i * 256; int r = idx >> 2, c = idx & 3;
            *(uint4*)&Bl[r * 40 + c * 8] = *(const uint4*)(BT + (size_t)r * 512 + kk + c * 8);
        }
        __syncthreads();
        bf16x8 af[4], bfr[4];
        #pragma unroll
        for (int m = 0; m < 4; ++m) af[m] = *(const bf16x8*)&Al[(m * 16 + l15) * 40 + lk];
        #pragma unroll
        for (int n = 0; n < 4; ++n) bfr[n] = *(const bf16x8*)&Bl[(w * 64 + n * 16 + l15) * 40 + lk];
        #pragma unroll
        for (int m = 0; m < 4; ++m)
            #pragma unroll
            for (int n = 0; n < 4; ++n)
                acc[m][n] = __builtin_amdgcn_mfma_f32_16x16x32_bf16(af[m], bfr[n], acc[m][n], 0, 0, 0);
        __syncthreads();
    }
    const int rbase = (l >> 4) * 4;
    float gg[4], bb[4];
    #pragma unroll
    for (int n = 0; n < 4; ++n) {
        int col = w * 64 + n * 16 + l15;
        float bv = b_out[col];
        gg[n] = ln_g[col]; bb[n] = ln_b[col];
        #pragma unroll
        for (int m = 0; m < 4; ++m)
            #pragma unroll
            for (int r = 0; r < 4; ++r)
                acc[m][n][r] += bv;
    }
    float s1[4][4], s2[4][4];
    #pragma unroll
    for (int m = 0; m < 4; ++m)
        #pragma unroll
        for (int r = 0; r < 4; ++r) {
            float a_ = 0.f, b_ = 0.f;
            #pragma unroll
            for (int n = 0; n < 4; ++n) {
                float v = acc[m][n][r];
                a_ += v; b_ += v * v;
            }
            s1[m][r] = a_; s2[m][r] = b_;
        }
    #pragma unroll
    for (int mask = 1; mask < 16; mask <<= 1)
        #pragma unroll
        for (int m = 0; m < 4; ++m)
            #pragma unroll
            for (int r = 0; r < 4; ++r) {
                s1[m][r] += __shfl_xor(s1[m][r], mask, 64);
                s2[m][r] += __shfl_xor(s2[m][r], mask, 64);
            }
    if (l15 == 0) {
        #pragma unroll
        for (int m = 0; m < 4; ++m)
            #pragma unroll
            for (int r = 0; r < 4; ++r) {
                int row = m * 16 + rbase + r;
                red[0][w][row] = s1[m][r];
                red[1][w][row] = s2[m][r];
            }
    }
    __syncthreads();
    #pragma unroll
    for (int m = 0; m < 4; ++m)
        #pragma unroll
        for (int r = 0; r < 4; ++r) {
            int row = m * 16 + rbase + r;
            float t1 = red[0][0][row] + red[0][1][row] + red[0][2][row] + red[0][3][row];
            float t2 = red[1][0][row] + red[1][1][row] + red[1][2][row] + red[1][3][row];
            float mu = t1 * (1.f / 256.f);
            float var = t2 * (1.f / 256.f) - mu * mu;
            float rs = rsqrtf(var + 1e-5f);
            #pragma unroll
            for (int n = 0; n < 4; ++n) {
                int col = w * 64 + n * 16 + l15;
                out[(size_t)(m0 + row) * 256 + col] = (acc[m][n][r] - mu) * rs * gg[n] + bb[n];
            }
        }
}

extern "C" void kernel_launch(void* const* d_in, const int* in_sizes, int n_in,
                              void* d_out, int out_size, void* d_ws, size_t ws_size,
                              hipStream_t stream)
{
    const float* x       = (const float*)d_in[0];
    const float* W_fproj = (const float*)d_in[1];
    const float* b_fproj = (const float*)d_in[2];
    const float* A_f     = (const float*)d_in[3];
    const float* W_fgate = (const float*)d_in[4];
    const float* b_fgate = (const float*)d_in[5];
    const float* W_bproj = (const float*)d_in[6];
    const float* b_bproj = (const float*)d_in[7];
    const float* A_b     = (const float*)d_in[8];
    const float* W_bgate = (const float*)d_in[9];
    const float* b_bgate = (const float*)d_in[10];
    const float* W_out   = (const float*)d_in[11];
    const float* b_out   = (const float*)d_in[12];
    const float* ln_g    = (const float*)d_in[13];
    const float* ln_b    = (const float*)d_in[14];

    char* ws = (char*)d_ws;
    ushort* value  = (ushort*)(ws + 0);             // 67108864 B  [row][512]
    float*  gw     = (float*) (ws + 67108864);      //  8388608 B  [dir][b][t][16]
    float*  L      = (float*) (ws + 75497472);      // 67108864 B  [dir][b][chunk][s][256]
    float*  P      = (float*) (ws + 142606336);     //   262144 B
    ushort* BTv    = (ushort*)(ws + 142868480);     //   262144 B
    ushort* WoT    = (ushort*)(ws + 143130624);     //   262144 B
    ushort* WgT    = (ushort*)(ws + 143392768);     //    16384 B
    float*  bias_v = (float*) (ws + 143409152);     //     2048 B

    prep_weights<<<1058, 256, 0, stream>>>(W_fproj, W_bproj, W_out, W_fgate, W_bgate,
                                           b_fproj, b_bproj, BTv, WoT, WgT, bias_v);
    gemm_value<<<1024, 256, 0, stream>>>(x, BTv, bias_v, value);
    gate_mfma<<<dim3(1024, 2), 256, 0, stream>>>(value, WgT, b_fgate, b_bgate, gw);
    pass_a<<<dim3(NC, NB, 2), 128, 0, stream>>>(value, gw, L, P);
    chunk_scan<<<256, 128, 0, stream>>>(L, P);
    pass_c<<<dim3(NC, NB, 2), 128, 0, stream>>>(value, gw, L, A_f, A_b);
    gemm_out_ln<<<1024, 256, 0, stream>>>(value, WoT, b_out, ln_g, ln_b, (float*)d_out);
}

// Round 4
// 223.535 us; speedup vs baseline: 1.2880x; 1.2880x over previous
//
#include <hip/hip_runtime.h>

#define SEQ   16384
#define NB    4
#define NROWS 65536
#define NC    512           // chunks per (dir,b)
#define CL    32            // chunk length

typedef short bf16x8 __attribute__((ext_vector_type(8)));
typedef float f32x4  __attribute__((ext_vector_type(4)));
typedef float f32x2  __attribute__((ext_vector_type(2)));

__device__ inline float bf2f(ushort u) {
    unsigned int t = ((unsigned int)u) << 16;
    float f; __builtin_memcpy(&f, &t, 4); return f;
}
__device__ inline ushort f2bf(float f) {
    unsigned int b; __builtin_memcpy(&b, &f, 4);
    unsigned int r = (b + 0x7FFFu + ((b >> 16) & 1u)) >> 16;
    return (ushort)r;
}

// ---------------- weight prep ----------------
// BTv [2][256 n][256 k], WoT [256 n][512 k], WgT [2][16 s][256 k], bias_v [512]
__global__ __launch_bounds__(256) void prep_weights(
    const float* __restrict__ Wf, const float* __restrict__ Wb,
    const float* __restrict__ Wo, const float* __restrict__ Wgf,
    const float* __restrict__ Wgb, const float* __restrict__ bfp,
    const float* __restrict__ bbp,
    ushort* __restrict__ BTv, ushort* __restrict__ WoT,
    ushort* __restrict__ WgT, float* __restrict__ bias_v)
{
    int idx = blockIdx.x * 256 + threadIdx.x;
    if (idx < 131072) {                 // BTv
        int dir = idx >> 16, j = idx & 65535, n = j >> 8, k = j & 255;
        const float* W = dir ? Wb : Wf;
        BTv[idx] = f2bf(W[k * 512 + 256 + n]);
    } else if (idx < 262144) {          // WoT
        int j = idx - 131072; int n = j >> 9, k = j & 511;
        WoT[j] = f2bf(Wo[k * 256 + n]);
    } else if (idx < 270336) {          // WgT
        int j = idx - 262144; int dir = j >> 12, jj = j & 4095, s = jj >> 8, k = jj & 255;
        WgT[j] = f2bf((dir ? Wgb : Wgf)[k * 16 + s]);
    } else if (idx < 270848) {          // bias_v
        int j = idx - 270336; int dir = j >> 8, n = j & 255;
        bias_v[j] = (dir ? bbp : bfp)[256 + n];
    }
}

// ---------------- value GEMM: 128x256 tile, 8 waves (2x4), grid.y = dir --------
__global__ __launch_bounds__(512) void gemm_value(
    const float* __restrict__ x, const ushort* __restrict__ BTv,
    const float* __restrict__ bias_v, ushort* __restrict__ value)
{
    __shared__ ushort Al[128 * 40];
    __shared__ ushort Bl[256 * 40];
    const int tid = threadIdx.x;
    const int m0 = blockIdx.x * 128, dir = blockIdx.y;
    const ushort* BT = BTv + dir * 65536;
    const int w = tid >> 6, l = tid & 63;
    const int wr = w >> 2, wc = w & 3;
    const int l15 = l & 15, lk = (l >> 4) * 8;
    f32x4 acc[4][4] = {};

    for (int kk = 0; kk < 256; kk += 32) {
        {   // A: 128 rows x 32 cols fp32 -> bf16, 8 elems/thread
            int r = tid >> 2, c = (tid & 3) * 8;
            const float* xp = x + (size_t)(m0 + r) * 256 + kk + c;
            float4 a = *(const float4*)xp;
            float4 b = *(const float4*)(xp + 4);
            ushort u[8];
            u[0] = f2bf(a.x); u[1] = f2bf(a.y); u[2] = f2bf(a.z); u[3] = f2bf(a.w);
            u[4] = f2bf(b.x); u[5] = f2bf(b.y); u[6] = f2bf(b.z); u[7] = f2bf(b.w);
            *(uint4*)&Al[r * 40 + c] = *(uint4*)u;
        }
        #pragma unroll
        for (int i = 0; i < 2; ++i) {   // B: 256 rows x 32 cols bf16
            int idx = tid + i * 512; int r = idx >> 2, c = idx & 3;
            *(uint4*)&Bl[r * 40 + c * 8] = *(const uint4*)(BT + (size_t)r * 256 + kk + c * 8);
        }
        __syncthreads();
        bf16x8 af[4], bfr[4];
        #pragma unroll
        for (int m = 0; m < 4; ++m) af[m] = *(const bf16x8*)&Al[(wr * 64 + m * 16 + l15) * 40 + lk];
        #pragma unroll
        for (int n = 0; n < 4; ++n) bfr[n] = *(const bf16x8*)&Bl[(wc * 64 + n * 16 + l15) * 40 + lk];
        #pragma unroll
        for (int m = 0; m < 4; ++m)
            #pragma unroll
            for (int n = 0; n < 4; ++n)
                acc[m][n] = __builtin_amdgcn_mfma_f32_16x16x32_bf16(af[m], bfr[n], acc[m][n], 0, 0, 0);
        __syncthreads();
    }
    const int rbase = (l >> 4) * 4;
    #pragma unroll
    for (int m = 0; m < 4; ++m)
        #pragma unroll
        for (int n = 0; n < 4; ++n) {
            int col = wc * 64 + n * 16 + l15;
            float bv = bias_v[dir * 256 + col];
            #pragma unroll
            for (int r = 0; r < 4; ++r) {
                int row = m0 + wr * 64 + m * 16 + rbase + r;
                value[(size_t)row * 512 + dir * 256 + col] = f2bf(acc[m][n][r] + bv);
            }
        }
}

// ---------------- gate via MFMA: 64 rows x 16 s, grid.y = dir ----------------
__global__ __launch_bounds__(256) void gate_mfma(
    const ushort* __restrict__ value, const ushort* __restrict__ WgT,
    const float* __restrict__ bgf, const float* __restrict__ bgb,
    float* __restrict__ gw)
{
    __shared__ ushort Av[64 * 264];
    const int tid = threadIdx.x;
    const int r0 = blockIdx.x * 64, dir = blockIdx.y;
    #pragma unroll
    for (int i = 0; i < 8; ++i) {
        int idx = tid + i * 256; int r = idx >> 5, c = idx & 31;
        *(uint4*)&Av[r * 264 + c * 8] =
            *(const uint4*)(value + (size_t)(r0 + r) * 512 + dir * 256 + c * 8);
    }
    __syncthreads();
    const int w = tid >> 6, l = tid & 63, l15 = l & 15, lk = (l >> 4) * 8;
    const ushort* Wg = WgT + dir * 4096;
    f32x4 acc = {};
    #pragma unroll
    for (int kk = 0; kk < 256; kk += 32) {
        bf16x8 af = *(const bf16x8*)&Av[(w * 16 + l15) * 264 + kk + lk];
        bf16x8 bf = *(const bf16x8*)(Wg + l15 * 256 + kk + lk);
        acc = __builtin_amdgcn_mfma_f32_16x16x32_bf16(af, bf, acc, 0, 0, 0);
    }
    const float* bg = dir ? bgb : bgf;
    float bgs = bg[l15];
    const int rbase = (l >> 4) * 4;
    #pragma unroll
    for (int r = 0; r < 4; ++r) {
        int gr = r0 + w * 16 + rbase + r;
        int b = gr >> 14, t = gr & 16383;
        float sv = 1.f / (1.f + __expf(-(acc[r] + bgs)));
        gw[((size_t)(dir * NB + b) * SEQ + t) * 16 + l15] = sv;
    }
}

// ---------------- pass A: local chunk-final states + decay products ----------------
__global__ __launch_bounds__(128) void pass_a(
    const ushort* __restrict__ value, const float* __restrict__ gw,
    float* __restrict__ L, float* __restrict__ P)
{
    const int chunk = blockIdx.x, b = blockIdx.y, dir = blockIdx.z;
    const int tid = threadIdx.x;
    __shared__ float gs[CL * 16];
    const float* gwd = gw + ((size_t)(dir * NB + b) * SEQ + chunk * CL) * 16;
    ((float4*)gs)[tid] = ((const float4*)gwd)[tid];
    __syncthreads();
    const ushort* vb = value + ((size_t)b * SEQ + chunk * CL) * 512 + dir * 256 + tid * 2;
    f32x2 c[16] = {};
    for (int i = 0; i < CL; ++i) {
        int row = dir ? (CL - 1 - i) : i;
        uint vv = *(const uint*)(vb + (size_t)row * 512);
        f32x2 v; v.x = bf2f((ushort)(vv & 0xffffu)); v.y = bf2f((ushort)(vv >> 16));
        float g[16];
        #pragma unroll
        for (int q = 0; q < 4; ++q)
            *(float4*)&g[q * 4] = *(const float4*)&gs[row * 16 + q * 4];
        #pragma unroll
        for (int s = 0; s < 16; ++s) {
            f32x2 gg; gg.x = g[s]; gg.y = g[s];
            c[s] = v + gg * (c[s] - v);
        }
    }
    float* Lp = L + ((size_t)(dir * NB + b) * NC + chunk) * 4096 + tid * 2;
    #pragma unroll
    for (int s = 0; s < 16; ++s)
        *(f32x2*)(Lp + s * 256) = c[s];
    if (tid < 16) {
        float p = 1.f;
        for (int t = 0; t < CL; ++t) p *= gs[t * 16 + tid];
        P[((size_t)(dir * NB + b) * NC + chunk) * 16 + tid] = p;
    }
}

// ---------------- pass B: chunk recurrence, 16-deep double-buffered loads --------
__global__ __launch_bounds__(128) void chunk_scan(
    float* __restrict__ L, const float* __restrict__ P)
{
    const int bid = blockIdx.x;          // 256 = 2 dir * 4 b * 16 s * 2 dhalf
    const int dir = bid >> 7, b = (bid >> 5) & 3, s = (bid >> 1) & 15, dh = bid & 1;
    const int d = dh * 128 + threadIdx.x;
    const size_t cb = (size_t)(dir * NB + b) * NC;
    float* Lb = L + cb * 4096 + s * 256 + d;
    const float* Pb = P + cb * 16 + s;
    float e = 0.f;
    float lA[16], pA[16], lB[16], pB[16];

#define LOADB(la, pa, ib) { _Pragma("unroll") \
    for (int j = 0; j < 16; ++j) { \
        int t = (ib) * 16 + j; int k = dir ? (NC - 1 - t) : t; \
        la[j] = Lb[(size_t)k * 4096]; pa[j] = Pb[k * 16]; } }
#define PROCB(la, pa, ib) { _Pragma("unroll") \
    for (int j = 0; j < 16; ++j) { \
        int t = (ib) * 16 + j; int k = dir ? (NC - 1 - t) : t; \
        Lb[(size_t)k * 4096] = e; e = pa[j] * e + la[j]; } }

    LOADB(lA, pA, 0)
    for (int ib = 0; ib < 32; ib += 2) {
        LOADB(lB, pB, ib + 1)
        PROCB(lA, pA, ib)
        if (ib + 2 < 32) { LOADB(lA, pA, ib + 2) }
        PROCB(lB, pB, ib + 1)
    }
#undef LOADB
#undef PROCB
}

// ---------------- pass C: re-run local scan with entry state, write in place ------
__global__ __launch_bounds__(128) void pass_c(
    ushort* __restrict__ value, const float* __restrict__ gw,
    const float* __restrict__ L, const float* __restrict__ A_f,
    const float* __restrict__ A_b)
{
    const int chunk = blockIdx.x, b = blockIdx.y, dir = blockIdx.z;
    const int tid = threadIdx.x;
    __shared__ float gs[CL * 16];
    const float* gwd = gw + ((size_t)(dir * NB + b) * SEQ + chunk * CL) * 16;
    ((float4*)gs)[tid] = ((const float4*)gwd)[tid];
    __syncthreads();
    ushort* vb = value + ((size_t)b * SEQ + chunk * CL) * 512 + dir * 256 + tid * 2;
    const float* Ad = dir ? A_b : A_f;
    const float* Lp = L + ((size_t)(dir * NB + b) * NC + chunk) * 4096 + tid * 2;
    f32x2 a[16], c[16];
    #pragma unroll
    for (int s = 0; s < 16; ++s) {
        a[s] = *(const f32x2*)(Ad + s * 256 + tid * 2);
        c[s] = *(const f32x2*)(Lp + s * 256);
    }
    for (int i = 0; i < CL; ++i) {
        int row = dir ? (CL - 1 - i) : i;
        uint vv = *(const uint*)(vb + (size_t)row * 512);
        f32x2 v; v.x = bf2f((ushort)(vv & 0xffffu)); v.y = bf2f((ushort)(vv >> 16));
        float g[16];
        #pragma unroll
        for (int q = 0; q < 4; ++q)
            *(float4*)&g[q * 4] = *(const float4*)&gs[row * 16 + q * 4];
        f32x2 o = {0.f, 0.f};
        #pragma unroll
        for (int s = 0; s < 16; ++s) {
            f32x2 gg; gg.x = g[s]; gg.y = g[s];
            c[s] = v + gg * (c[s] - v);
            o += a[s] * (gg * c[s]);
        }
        uint outv = (uint)f2bf(o.x) | ((uint)f2bf(o.y) << 16);
        *(uint*)(vb + (size_t)row * 512) = outv;
    }
}

// ---------------- out GEMM: 128x256 tile, K=512, fused LayerNorm ----------------
__global__ __launch_bounds__(512) void gemm_out_ln(
    const ushort* __restrict__ A, const ushort* __restrict__ BT,
    const float* __restrict__ b_out, const float* __restrict__ ln_g,
    const float* __restrict__ ln_b, float* __restrict__ out)
{
    __shared__ ushort Al[128 * 40];
    __shared__ ushort Bl[256 * 40];
    __shared__ float red[2][2][4][64];
    const int tid = threadIdx.x;
    const int m0 = blockIdx.x * 128;
    const int w = tid >> 6, l = tid & 63;
    const int wr = w >> 2, wc = w & 3;
    const int l15 = l & 15, lk = (l >> 4) * 8;
    f32x4 acc[4][4] = {};

    for (int kk = 0; kk < 512; kk += 32) {
        {   // A: 128 rows x 32 cols bf16
            int r = tid >> 2, c = tid & 3;
            *(uint4*)&Al[r * 40 + c * 8] = *(const uint4*)(A + (size_t)(m0 + r) * 512 + kk + c * 8);
        }
        #pragma unroll
        for (int i = 0; i < 2; ++i) {   // B: 256 rows x 32 cols
            int idx = tid + i * 512; int r = idx >> 2, c = idx & 3;
            *(uint4*)&Bl[r * 40 + c * 8] = *(const uint4*)(BT + (size_t)r * 512 + kk + c * 8);
        }
        __syncthreads();
        bf16x8 af[4], bfr[4];
        #pragma unroll
        for (int m = 0; m < 4; ++m) af[m] = *(const bf16x8*)&Al[(wr * 64 + m * 16 + l15) * 40 + lk];
        #pragma unroll
        for (int n = 0; n < 4; ++n) bfr[n] = *(const bf16x8*)&Bl[(wc * 64 + n * 16 + l15) * 40 + lk];
        #pragma unroll
        for (int m = 0; m < 4; ++m)
            #pragma unroll
            for (int n = 0; n < 4; ++n)
                acc[m][n] = __builtin_amdgcn_mfma_f32_16x16x32_bf16(af[m], bfr[n], acc[m][n], 0, 0, 0);
        __syncthreads();
    }
    const int rbase = (l >> 4) * 4;
    float gg[4], bb[4];
    #pragma unroll
    for (int n = 0; n < 4; ++n) {
        int col = wc * 64 + n * 16 + l15;
        float bv = b_out[col];
        gg[n] = ln_g[col]; bb[n] = ln_b[col];
        #pragma unroll
        for (int m = 0; m < 4; ++m)
            #pragma unroll
            for (int r = 0; r < 4; ++r)
                acc[m][n][r] += bv;
    }
    float s1[4][4], s2[4][4];
    #pragma unroll
    for (int m = 0; m < 4; ++m)
        #pragma unroll
        for (int r = 0; r < 4; ++r) {
            float a_ = 0.f, b_ = 0.f;
            #pragma unroll
            for (int n = 0; n < 4; ++n) {
                float v = acc[m][n][r];
                a_ += v; b_ += v * v;
            }
            s1[m][r] = a_; s2[m][r] = b_;
        }
    #pragma unroll
    for (int mask = 1; mask < 16; mask <<= 1)
        #pragma unroll
        for (int m = 0; m < 4; ++m)
            #pragma unroll
            for (int r = 0; r < 4; ++r) {
                s1[m][r] += __shfl_xor(s1[m][r], mask, 64);
                s2[m][r] += __shfl_xor(s2[m][r], mask, 64);
            }
    if (l15 == 0) {
        #pragma unroll
        for (int m = 0; m < 4; ++m)
            #pragma unroll
            for (int r = 0; r < 4; ++r) {
                int row = m * 16 + rbase + r;
                red[0][wr][wc][row] = s1[m][r];
                red[1][wr][wc][row] = s2[m][r];
            }
    }
    __syncthreads();
    #pragma unroll
    for (int m = 0; m < 4; ++m)
        #pragma unroll
        for (int r = 0; r < 4; ++r) {
            int row = m * 16 + rbase + r;
            float t1 = red[0][wr][0][row] + red[0][wr][1][row] + red[0][wr][2][row] + red[0][wr][3][row];
            float t2 = red[1][wr][0][row] + red[1][wr][1][row] + red[1][wr][2][row] + red[1][wr][3][row];
            float mu = t1 * (1.f / 256.f);
            float var = t2 * (1.f / 256.f) - mu * mu;
            float rs = rsqrtf(var + 1e-5f);
            #pragma unroll
            for (int n = 0; n < 4; ++n) {
                int col = wc * 64 + n * 16 + l15;
                out[(size_t)(m0 + wr * 64 + row) * 256 + col] = (acc[m][n][r] - mu) * rs * gg[n] + bb[n];
            }
        }
}

extern "C" void kernel_launch(void* const* d_in, const int* in_sizes, int n_in,
                              void* d_out, int out_size, void* d_ws, size_t ws_size,
                              hipStream_t stream)
{
    const float* x       = (const float*)d_in[0];
    const float* W_fproj = (const float*)d_in[1];
    const float* b_fproj = (const float*)d_in[2];
    const float* A_f     = (const float*)d_in[3];
    const float* W_fgate = (const float*)d_in[4];
    const float* b_fgate = (const float*)d_in[5];
    const float* W_bproj = (const float*)d_in[6];
    const float* b_bproj = (const float*)d_in[7];
    const float* A_b     = (const float*)d_in[8];
    const float* W_bgate = (const float*)d_in[9];
    const float* b_bgate = (const float*)d_in[10];
    const float* W_out   = (const float*)d_in[11];
    const float* b_out   = (const float*)d_in[12];
    const float* ln_g    = (const float*)d_in[13];
    const float* ln_b    = (const float*)d_in[14];

    char* ws = (char*)d_ws;
    ushort* value  = (ushort*)(ws + 0);             // 67108864 B  [row][512]
    float*  gw     = (float*) (ws + 67108864);      //  8388608 B  [dir][b][t][16]
    float*  L      = (float*) (ws + 75497472);      // 67108864 B  [dir][b][chunk][s][256]
    float*  P      = (float*) (ws + 142606336);     //   262144 B
    ushort* BTv    = (ushort*)(ws + 142868480);     //   262144 B
    ushort* WoT    = (ushort*)(ws + 143130624);     //   262144 B
    ushort* WgT    = (ushort*)(ws + 143392768);     //    16384 B
    float*  bias_v = (float*) (ws + 143409152);     //     2048 B

    prep_weights<<<1058, 256, 0, stream>>>(W_fproj, W_bproj, W_out, W_fgate, W_bgate,
                                           b_fproj, b_bproj, BTv, WoT, WgT, bias_v);
    gemm_value<<<dim3(512, 2), 512, 0, stream>>>(x, BTv, bias_v, value);
    gate_mfma<<<dim3(1024, 2), 256, 0, stream>>>(value, WgT, b_fgate, b_bgate, gw);
    pass_a<<<dim3(NC, NB, 2), 128, 0, stream>>>(value, gw, L, P);
    chunk_scan<<<256, 128, 0, stream>>>(L, P);
    pass_c<<<dim3(NC, NB, 2), 128, 0, stream>>>(value, gw, L, A_f, A_b);
    gemm_out_ln<<<512, 512, 0, stream>>>(value, WoT, b_out, ln_g, ln_b, (float*)d_out);
}

// Round 5
// 207.288 us; speedup vs baseline: 1.3890x; 1.0784x over previous
//
#include <hip/hip_runtime.h>

#define SEQ   16384
#define NB    4
#define NROWS 65536
#define NC    512           // chunks per (dir,b)
#define CL    32            // chunk length

typedef short bf16x8 __attribute__((ext_vector_type(8)));
typedef float f32x4  __attribute__((ext_vector_type(4)));
typedef float f32x2  __attribute__((ext_vector_type(2)));

__device__ inline float bf2f(ushort u) {
    unsigned int t = ((unsigned int)u) << 16;
    float f; __builtin_memcpy(&f, &t, 4); return f;
}
__device__ inline ushort f2bf(float f) {
    unsigned int b; __builtin_memcpy(&b, &f, 4);
    unsigned int r = (b + 0x7FFFu + ((b >> 16) & 1u)) >> 16;
    return (ushort)r;
}

// ---------------- weight prep ----------------
// BTv [2][256 n][256 k], WoT [256 n][512 k], WgT [2][16 s][256 k], bias_v [512]
__global__ __launch_bounds__(256) void prep_weights(
    const float* __restrict__ Wf, const float* __restrict__ Wb,
    const float* __restrict__ Wo, const float* __restrict__ Wgf,
    const float* __restrict__ Wgb, const float* __restrict__ bfp,
    const float* __restrict__ bbp,
    ushort* __restrict__ BTv, ushort* __restrict__ WoT,
    ushort* __restrict__ WgT, float* __restrict__ bias_v)
{
    int idx = blockIdx.x * 256 + threadIdx.x;
    if (idx < 131072) {                 // BTv
        int dir = idx >> 16, j = idx & 65535, n = j >> 8, k = j & 255;
        const float* W = dir ? Wb : Wf;
        BTv[idx] = f2bf(W[k * 512 + 256 + n]);
    } else if (idx < 262144) {          // WoT
        int j = idx - 131072; int n = j >> 9, k = j & 511;
        WoT[j] = f2bf(Wo[k * 256 + n]);
    } else if (idx < 270336) {          // WgT
        int j = idx - 262144; int dir = j >> 12, jj = j & 4095, s = jj >> 8, k = jj & 255;
        WgT[j] = f2bf((dir ? Wgb : Wgf)[k * 16 + s]);
    } else if (idx < 270848) {          // bias_v
        int j = idx - 270336; int dir = j >> 8, n = j & 255;
        bias_v[j] = (dir ? bbp : bfp)[256 + n];
    }
}

// ---------------- value GEMM: 128x256 tile, 8 waves (2x4), grid.y = dir --------
__global__ __launch_bounds__(512) void gemm_value(
    const float* __restrict__ x, const ushort* __restrict__ BTv,
    const float* __restrict__ bias_v, ushort* __restrict__ value)
{
    __shared__ ushort Al[128 * 40];
    __shared__ ushort Bl[256 * 40];
    const int tid = threadIdx.x;
    const int m0 = blockIdx.x * 128, dir = blockIdx.y;
    const ushort* BT = BTv + dir * 65536;
    const int w = tid >> 6, l = tid & 63;
    const int wr = w >> 2, wc = w & 3;
    const int l15 = l & 15, lk = (l >> 4) * 8;
    f32x4 acc[4][4] = {};

    for (int kk = 0; kk < 256; kk += 32) {
        {   // A: 128 rows x 32 cols fp32 -> bf16, 8 elems/thread
            int r = tid >> 2, c = (tid & 3) * 8;
            const float* xp = x + (size_t)(m0 + r) * 256 + kk + c;
            float4 a = *(const float4*)xp;
            float4 b = *(const float4*)(xp + 4);
            ushort u[8];
            u[0] = f2bf(a.x); u[1] = f2bf(a.y); u[2] = f2bf(a.z); u[3] = f2bf(a.w);
            u[4] = f2bf(b.x); u[5] = f2bf(b.y); u[6] = f2bf(b.z); u[7] = f2bf(b.w);
            *(uint4*)&Al[r * 40 + c] = *(uint4*)u;
        }
        #pragma unroll
        for (int i = 0; i < 2; ++i) {   // B: 256 rows x 32 cols bf16
            int idx = tid + i * 512; int r = idx >> 2, c = idx & 3;
            *(uint4*)&Bl[r * 40 + c * 8] = *(const uint4*)(BT + (size_t)r * 256 + kk + c * 8);
        }
        __syncthreads();
        bf16x8 af[4], bfr[4];
        #pragma unroll
        for (int m = 0; m < 4; ++m) af[m] = *(const bf16x8*)&Al[(wr * 64 + m * 16 + l15) * 40 + lk];
        #pragma unroll
        for (int n = 0; n < 4; ++n) bfr[n] = *(const bf16x8*)&Bl[(wc * 64 + n * 16 + l15) * 40 + lk];
        #pragma unroll
        for (int m = 0; m < 4; ++m)
            #pragma unroll
            for (int n = 0; n < 4; ++n)
                acc[m][n] = __builtin_amdgcn_mfma_f32_16x16x32_bf16(af[m], bfr[n], acc[m][n], 0, 0, 0);
        __syncthreads();
    }
    const int rbase = (l >> 4) * 4;
    #pragma unroll
    for (int m = 0; m < 4; ++m)
        #pragma unroll
        for (int n = 0; n < 4; ++n) {
            int col = wc * 64 + n * 16 + l15;
            float bv = bias_v[dir * 256 + col];
            #pragma unroll
            for (int r = 0; r < 4; ++r) {
                int row = m0 + wr * 64 + m * 16 + rbase + r;
                value[(size_t)row * 512 + dir * 256 + col] = f2bf(acc[m][n][r] + bv);
            }
        }
}

// ------- fused gate (MFMA) + pass A local scan: 64 rows = 2 chunks, grid.y = dir
__global__ __launch_bounds__(256, 3) void gate_scan(
    const ushort* __restrict__ value, const ushort* __restrict__ WgT,
    const float* __restrict__ bgf, const float* __restrict__ bgb,
    float* __restrict__ gw, float* __restrict__ L, float* __restrict__ P)
{
    __shared__ ushort Av[64 * 264];
    __shared__ float gsm[64 * 16];
    const int tid = threadIdx.x;
    const int r0 = blockIdx.x * 64, dir = blockIdx.y;
    #pragma unroll
    for (int i = 0; i < 8; ++i) {
        int idx = tid + i * 256; int r = idx >> 5, c = idx & 31;
        *(uint4*)&Av[r * 264 + c * 8] =
            *(const uint4*)(value + (size_t)(r0 + r) * 512 + dir * 256 + c * 8);
    }
    __syncthreads();
    const int w = tid >> 6, l = tid & 63, l15 = l & 15, lk = (l >> 4) * 8;
    const ushort* Wg = WgT + dir * 4096;
    f32x4 acc = {};
    #pragma unroll
    for (int kk = 0; kk < 256; kk += 32) {
        bf16x8 af = *(const bf16x8*)&Av[(w * 16 + l15) * 264 + kk + lk];
        bf16x8 bf = *(const bf16x8*)(Wg + l15 * 256 + kk + lk);
        acc = __builtin_amdgcn_mfma_f32_16x16x32_bf16(af, bf, acc, 0, 0, 0);
    }
    const float bgs = (dir ? bgb : bgf)[l15];
    const int rbase = (l >> 4) * 4;
    const int b = r0 >> 14, t0 = r0 & 16383;
    #pragma unroll
    for (int r = 0; r < 4; ++r) {
        int lr = w * 16 + rbase + r;
        float sv = 1.f / (1.f + __expf(-(acc[r] + bgs)));
        gsm[lr * 16 + l15] = sv;
        gw[((size_t)(dir * NB + b) * SEQ + t0 + lr) * 16 + l15] = sv;
    }
    __syncthreads();
    // local scan: 2 chunks x 128 d-pairs
    const int ci = tid >> 7, dp = tid & 127;
    const int chunk = (t0 >> 5) + ci;
    f32x2 c[16] = {};
    for (int i = 0; i < CL; ++i) {
        int row = dir ? (CL - 1 - i) : i;
        uint vv = *(const uint*)&Av[(ci * 32 + row) * 264 + dp * 2];
        f32x2 v; v.x = bf2f((ushort)(vv & 0xffffu)); v.y = bf2f((ushort)(vv >> 16));
        float g[16];
        #pragma unroll
        for (int q = 0; q < 4; ++q)
            *(float4*)&g[q * 4] = *(const float4*)&gsm[(ci * 32 + row) * 16 + q * 4];
        #pragma unroll
        for (int s = 0; s < 16; ++s) {
            f32x2 gg; gg.x = g[s]; gg.y = g[s];
            c[s] = v + gg * (c[s] - v);
        }
    }
    float* Lp = L + ((size_t)(dir * NB + b) * NC + chunk) * 4096 + dp * 2;
    #pragma unroll
    for (int s = 0; s < 16; ++s)
        *(f32x2*)(Lp + s * 256) = c[s];
    if (dp < 16) {
        float p = 1.f;
        for (int t = 0; t < CL; ++t) p *= gsm[(ci * 32 + t) * 16 + dp];
        P[((size_t)(dir * NB + b) * NC + chunk) * 16 + dp] = p;
    }
}

// ---------------- pass B: chunk recurrence, 16-deep double-buffered loads --------
__global__ __launch_bounds__(128, 2) void chunk_scan(
    float* __restrict__ L, const float* __restrict__ P)
{
    const int bid = blockIdx.x;          // 256 = 2 dir * 4 b * 16 s * 2 dhalf
    const int dir = bid >> 7, b = (bid >> 5) & 3, s = (bid >> 1) & 15, dh = bid & 1;
    const int d = dh * 128 + threadIdx.x;
    const size_t cb = (size_t)(dir * NB + b) * NC;
    float* Lb = L + cb * 4096 + s * 256 + d;
    const float* Pb = P + cb * 16 + s;
    float e = 0.f;
    float lA[16], pA[16], lB[16], pB[16];

#define LOADB(la, pa, ib) { _Pragma("unroll") \
    for (int j = 0; j < 16; ++j) { \
        int t = (ib) * 16 + j; int k = dir ? (NC - 1 - t) : t; \
        la[j] = Lb[(size_t)k * 4096]; pa[j] = Pb[k * 16]; } }
#define PROCB(la, pa, ib) { _Pragma("unroll") \
    for (int j = 0; j < 16; ++j) { \
        int t = (ib) * 16 + j; int k = dir ? (NC - 1 - t) : t; \
        Lb[(size_t)k * 4096] = e; e = pa[j] * e + la[j]; } }

    LOADB(lA, pA, 0)
    for (int ib = 0; ib < 32; ib += 2) {
        LOADB(lB, pB, ib + 1)
        PROCB(lA, pA, ib)
        if (ib + 2 < 32) { LOADB(lA, pA, ib + 2) }
        PROCB(lB, pB, ib + 1)
    }
#undef LOADB
#undef PROCB
}

// ---------------- pass C: local scan w/ entry state, 4-deep v prefetch ----------
__global__ __launch_bounds__(128, 3) void pass_c(
    ushort* __restrict__ value, const float* __restrict__ gw,
    const float* __restrict__ L, const float* __restrict__ A_f,
    const float* __restrict__ A_b)
{
    const int chunk = blockIdx.x, b = blockIdx.y, dir = blockIdx.z;
    const int tid = threadIdx.x;
    __shared__ float gs[CL * 16];
    const float* gwd = gw + ((size_t)(dir * NB + b) * SEQ + chunk * CL) * 16;
    ((float4*)gs)[tid] = ((const float4*)gwd)[tid];
    __syncthreads();
    ushort* vb = value + ((size_t)b * SEQ + chunk * CL) * 512 + dir * 256 + tid * 2;
    const float* Ad = dir ? A_b : A_f;
    const float* Lp = L + ((size_t)(dir * NB + b) * NC + chunk) * 4096 + tid * 2;
    f32x2 a[16], c[16];
    #pragma unroll
    for (int s = 0; s < 16; ++s) {
        a[s] = *(const f32x2*)(Ad + s * 256 + tid * 2);
        c[s] = *(const f32x2*)(Lp + s * 256);
    }
    uint vbuf[4];
    #pragma unroll
    for (int j = 0; j < 4; ++j) {
        int row = dir ? (CL - 1 - j) : j;
        vbuf[j] = *(const uint*)(vb + (size_t)row * 512);
    }
    for (int i0 = 0; i0 < CL; i0 += 4) {
        uint vcur[4];
        #pragma unroll
        for (int j = 0; j < 4; ++j) vcur[j] = vbuf[j];
        if (i0 + 4 < CL) {
            #pragma unroll
            for (int j = 0; j < 4; ++j) {
                int t = i0 + 4 + j;
                int row = dir ? (CL - 1 - t) : t;
                vbuf[j] = *(const uint*)(vb + (size_t)row * 512);
            }
        }
        #pragma unroll
        for (int j = 0; j < 4; ++j) {
            int t = i0 + j;
            int row = dir ? (CL - 1 - t) : t;
            f32x2 v; v.x = bf2f((ushort)(vcur[j] & 0xffffu)); v.y = bf2f((ushort)(vcur[j] >> 16));
            float g[16];
            #pragma unroll
            for (int q = 0; q < 4; ++q)
                *(float4*)&g[q * 4] = *(const float4*)&gs[row * 16 + q * 4];
            f32x2 o = {0.f, 0.f};
            #pragma unroll
            for (int s = 0; s < 16; ++s) {
                f32x2 gg; gg.x = g[s]; gg.y = g[s];
                c[s] = v + gg * (c[s] - v);
                o += a[s] * (gg * c[s]);
            }
            uint outv = (uint)f2bf(o.x) | ((uint)f2bf(o.y) << 16);
            *(uint*)(vb + (size_t)row * 512) = outv;
        }
    }
}

// ---------------- out GEMM: 128x256 tile, K=512, fused LayerNorm ----------------
__global__ __launch_bounds__(512) void gemm_out_ln(
    const ushort* __restrict__ A, const ushort* __restrict__ BT,
    const float* __restrict__ b_out, const float* __restrict__ ln_g,
    const float* __restrict__ ln_b, float* __restrict__ out)
{
    __shared__ ushort Al[128 * 40];
    __shared__ ushort Bl[256 * 40];
    __shared__ float red[2][2][4][64];
    const int tid = threadIdx.x;
    const int m0 = blockIdx.x * 128;
    const int w = tid >> 6, l = tid & 63;
    const int wr = w >> 2, wc = w & 3;
    const int l15 = l & 15, lk = (l >> 4) * 8;
    f32x4 acc[4][4] = {};

    for (int kk = 0; kk < 512; kk += 32) {
        {   // A: 128 rows x 32 cols bf16
            int r = tid >> 2, c = tid & 3;
            *(uint4*)&Al[r * 40 + c * 8] = *(const uint4*)(A + (size_t)(m0 + r) * 512 + kk + c * 8);
        }
        #pragma unroll
        for (int i = 0; i < 2; ++i) {   // B: 256 rows x 32 cols
            int idx = tid + i * 512; int r = idx >> 2, c = idx & 3;
            *(uint4*)&Bl[r * 40 + c * 8] = *(const uint4*)(BT + (size_t)r * 512 + kk + c * 8);
        }
        __syncthreads();
        bf16x8 af[4], bfr[4];
        #pragma unroll
        for (int m = 0; m < 4; ++m) af[m] = *(const bf16x8*)&Al[(wr * 64 + m * 16 + l15) * 40 + lk];
        #pragma unroll
        for (int n = 0; n < 4; ++n) bfr[n] = *(const bf16x8*)&Bl[(wc * 64 + n * 16 + l15) * 40 + lk];
        #pragma unroll
        for (int m = 0; m < 4; ++m)
            #pragma unroll
            for (int n = 0; n < 4; ++n)
                acc[m][n] = __builtin_amdgcn_mfma_f32_16x16x32_bf16(af[m], bfr[n], acc[m][n], 0, 0, 0);
        __syncthreads();
    }
    const int rbase = (l >> 4) * 4;
    float gg[4], bb[4];
    #pragma unroll
    for (int n = 0; n < 4; ++n) {
        int col = wc * 64 + n * 16 + l15;
        float bv = b_out[col];
        gg[n] = ln_g[col]; bb[n] = ln_b[col];
        #pragma unroll
        for (int m = 0; m < 4; ++m)
            #pragma unroll
            for (int r = 0; r < 4; ++r)
                acc[m][n][r] += bv;
    }
    float s1[4][4], s2[4][4];
    #pragma unroll
    for (int m = 0; m < 4; ++m)
        #pragma unroll
        for (int r = 0; r < 4; ++r) {
            float a_ = 0.f, b_ = 0.f;
            #pragma unroll
            for (int n = 0; n < 4; ++n) {
                float v = acc[m][n][r];
                a_ += v; b_ += v * v;
            }
            s1[m][r] = a_; s2[m][r] = b_;
        }
    #pragma unroll
    for (int mask = 1; mask < 16; mask <<= 1)
        #pragma unroll
        for (int m = 0; m < 4; ++m)
            #pragma unroll
            for (int r = 0; r < 4; ++r) {
                s1[m][r] += __shfl_xor(s1[m][r], mask, 64);
                s2[m][r] += __shfl_xor(s2[m][r], mask, 64);
            }
    if (l15 == 0) {
        #pragma unroll
        for (int m = 0; m < 4; ++m)
            #pragma unroll
            for (int r = 0; r < 4; ++r) {
                int row = m * 16 + rbase + r;
                red[0][wr][wc][row] = s1[m][r];
                red[1][wr][wc][row] = s2[m][r];
            }
    }
    __syncthreads();
    #pragma unroll
    for (int m = 0; m < 4; ++m)
        #pragma unroll
        for (int r = 0; r < 4; ++r) {
            int row = m * 16 + rbase + r;
            float t1 = red[0][wr][0][row] + red[0][wr][1][row] + red[0][wr][2][row] + red[0][wr][3][row];
            float t2 = red[1][wr][0][row] + red[1][wr][1][row] + red[1][wr][2][row] + red[1][wr][3][row];
            float mu = t1 * (1.f / 256.f);
            float var = t2 * (1.f / 256.f) - mu * mu;
            float rs = rsqrtf(var + 1e-5f);
            #pragma unroll
            for (int n = 0; n < 4; ++n) {
                int col = wc * 64 + n * 16 + l15;
                out[(size_t)(m0 + wr * 64 + row) * 256 + col] = (acc[m][n][r] - mu) * rs * gg[n] + bb[n];
            }
        }
}

extern "C" void kernel_launch(void* const* d_in, const int* in_sizes, int n_in,
                              void* d_out, int out_size, void* d_ws, size_t ws_size,
                              hipStream_t stream)
{
    const float* x       = (const float*)d_in[0];
    const float* W_fproj = (const float*)d_in[1];
    const float* b_fproj = (const float*)d_in[2];
    const float* A_f     = (const float*)d_in[3];
    const float* W_fgate = (const float*)d_in[4];
    const float* b_fgate = (const float*)d_in[5];
    const float* W_bproj = (const float*)d_in[6];
    const float* b_bproj = (const float*)d_in[7];
    const float* A_b     = (const float*)d_in[8];
    const float* W_bgate = (const float*)d_in[9];
    const float* b_bgate = (const float*)d_in[10];
    const float* W_out   = (const float*)d_in[11];
    const float* b_out   = (const float*)d_in[12];
    const float* ln_g    = (const float*)d_in[13];
    const float* ln_b    = (const float*)d_in[14];

    char* ws = (char*)d_ws;
    ushort* value  = (ushort*)(ws + 0);             // 67108864 B  [row][512]
    float*  gw     = (float*) (ws + 67108864);      //  8388608 B  [dir][b][t][16]
    float*  L      = (float*) (ws + 75497472);      // 67108864 B  [dir][b][chunk][s][256]
    float*  P      = (float*) (ws + 142606336);     //   262144 B
    ushort* BTv    = (ushort*)(ws + 142868480);     //   262144 B
    ushort* WoT    = (ushort*)(ws + 143130624);     //   262144 B
    ushort* WgT    = (ushort*)(ws + 143392768);     //    16384 B
    float*  bias_v = (float*) (ws + 143409152);     //     2048 B

    prep_weights<<<1058, 256, 0, stream>>>(W_fproj, W_bproj, W_out, W_fgate, W_bgate,
                                           b_fproj, b_bproj, BTv, WoT, WgT, bias_v);
    gemm_value<<<dim3(512, 2), 512, 0, stream>>>(x, BTv, bias_v, value);
    gate_scan<<<dim3(1024, 2), 256, 0, stream>>>(value, WgT, b_fgate, b_bgate, gw, L, P);
    chunk_scan<<<256, 128, 0, stream>>>(L, P);
    pass_c<<<dim3(NC, NB, 2), 128, 0, stream>>>(value, gw, L, A_f, A_b);
    gemm_out_ln<<<512, 512, 0, stream>>>(value, WoT, b_out, ln_g, ln_b, (float*)d_out);
}

// Round 6
// 201.797 us; speedup vs baseline: 1.4268x; 1.0272x over previous
//
#include <hip/hip_runtime.h>

#define SEQ   16384
#define NB    4
#define NROWS 65536
#define NC    512           // chunks per (dir,b)
#define CL    32            // chunk length

typedef short bf16x8 __attribute__((ext_vector_type(8)));
typedef float f32x4  __attribute__((ext_vector_type(4)));
typedef float f32x2  __attribute__((ext_vector_type(2)));

__device__ inline float bf2f(ushort u) {
    unsigned int t = ((unsigned int)u) << 16;
    float f; __builtin_memcpy(&f, &t, 4); return f;
}
__device__ inline float bflo(uint u) {
    uint t = u << 16; float f; __builtin_memcpy(&f, &t, 4); return f;
}
__device__ inline float bfhi(uint u) {
    uint t = u & 0xffff0000u; float f; __builtin_memcpy(&f, &t, 4); return f;
}
__device__ inline ushort f2bf(float f) {
    unsigned int b; __builtin_memcpy(&b, &f, 4);
    unsigned int r = (b + 0x7FFFu + ((b >> 16) & 1u)) >> 16;
    return (ushort)r;
}

// ---------------- weight prep ----------------
// BTv [2][256 n][256 k], WoT [256 n][512 k], WgT [2][16 s][256 k], bias_v [512],
// AsT [2][256 d][16 s] fp32
__global__ __launch_bounds__(256) void prep_weights(
    const float* __restrict__ Wf, const float* __restrict__ Wb,
    const float* __restrict__ Wo, const float* __restrict__ Wgf,
    const float* __restrict__ Wgb, const float* __restrict__ bfp,
    const float* __restrict__ bbp, const float* __restrict__ A_f,
    const float* __restrict__ A_b,
    ushort* __restrict__ BTv, ushort* __restrict__ WoT,
    ushort* __restrict__ WgT, float* __restrict__ bias_v,
    float* __restrict__ AsT)
{
    int idx = blockIdx.x * 256 + threadIdx.x;
    if (idx < 131072) {                 // BTv
        int dir = idx >> 16, j = idx & 65535, n = j >> 8, k = j & 255;
        const float* W = dir ? Wb : Wf;
        BTv[idx] = f2bf(W[k * 512 + 256 + n]);
    } else if (idx < 262144) {          // WoT
        int j = idx - 131072; int n = j >> 9, k = j & 511;
        WoT[j] = f2bf(Wo[k * 256 + n]);
    } else if (idx < 270336) {          // WgT
        int j = idx - 262144; int dir = j >> 12, jj = j & 4095, s = jj >> 8, k = jj & 255;
        WgT[j] = f2bf((dir ? Wgb : Wgf)[k * 16 + s]);
    } else if (idx < 270848) {          // bias_v
        int j = idx - 270336; int dir = j >> 8, n = j & 255;
        bias_v[j] = (dir ? bbp : bfp)[256 + n];
    } else if (idx < 279040) {          // AsT transpose
        int j = idx - 270848; int dir = j >> 12, jj = j & 4095, d = jj >> 4, s = jj & 15;
        AsT[j] = (dir ? A_b : A_f)[s * 256 + d];
    }
}

// ---------------- value GEMM: 128x256 tile, 8 waves (2x4), grid.y = dir --------
__global__ __launch_bounds__(512) void gemm_value(
    const float* __restrict__ x, const ushort* __restrict__ BTv,
    const float* __restrict__ bias_v, ushort* __restrict__ value)
{
    __shared__ ushort Al[128 * 40];
    __shared__ ushort Bl[256 * 40];
    const int tid = threadIdx.x;
    const int m0 = blockIdx.x * 128, dir = blockIdx.y;
    const ushort* BT = BTv + dir * 65536;
    const int w = tid >> 6, l = tid & 63;
    const int wr = w >> 2, wc = w & 3;
    const int l15 = l & 15, lk = (l >> 4) * 8;
    f32x4 acc[4][4] = {};

    for (int kk = 0; kk < 256; kk += 32) {
        {   // A: 128 rows x 32 cols fp32 -> bf16, 8 elems/thread
            int r = tid >> 2, c = (tid & 3) * 8;
            const float* xp = x + (size_t)(m0 + r) * 256 + kk + c;
            float4 a = *(const float4*)xp;
            float4 b = *(const float4*)(xp + 4);
            ushort u[8];
            u[0] = f2bf(a.x); u[1] = f2bf(a.y); u[2] = f2bf(a.z); u[3] = f2bf(a.w);
            u[4] = f2bf(b.x); u[5] = f2bf(b.y); u[6] = f2bf(b.z); u[7] = f2bf(b.w);
            *(uint4*)&Al[r * 40 + c] = *(uint4*)u;
        }
        #pragma unroll
        for (int i = 0; i < 2; ++i) {   // B: 256 rows x 32 cols bf16
            int idx = tid + i * 512; int r = idx >> 2, c = idx & 3;
            *(uint4*)&Bl[r * 40 + c * 8] = *(const uint4*)(BT + (size_t)r * 256 + kk + c * 8);
        }
        __syncthreads();
        bf16x8 af[4], bfr[4];
        #pragma unroll
        for (int m = 0; m < 4; ++m) af[m] = *(const bf16x8*)&Al[(wr * 64 + m * 16 + l15) * 40 + lk];
        #pragma unroll
        for (int n = 0; n < 4; ++n) bfr[n] = *(const bf16x8*)&Bl[(wc * 64 + n * 16 + l15) * 40 + lk];
        #pragma unroll
        for (int m = 0; m < 4; ++m)
            #pragma unroll
            for (int n = 0; n < 4; ++n)
                acc[m][n] = __builtin_amdgcn_mfma_f32_16x16x32_bf16(af[m], bfr[n], acc[m][n], 0, 0, 0);
        __syncthreads();
    }
    const int rbase = (l >> 4) * 4;
    #pragma unroll
    for (int m = 0; m < 4; ++m)
        #pragma unroll
        for (int n = 0; n < 4; ++n) {
            int col = wc * 64 + n * 16 + l15;
            float bv = bias_v[dir * 256 + col];
            #pragma unroll
            for (int r = 0; r < 4; ++r) {
                int row = m0 + wr * 64 + m * 16 + rbase + r;
                value[(size_t)row * 512 + dir * 256 + col] = f2bf(acc[m][n][r] + bv);
            }
        }
}

// ------- fused gate (MFMA) + pass A local scan: 64 rows = 2 chunks, grid.y = dir
// L16 layout: [dir][b][chunk][d 256][s 16] bf16
__global__ __launch_bounds__(256, 3) void gate_scan(
    const ushort* __restrict__ value, const ushort* __restrict__ WgT,
    const float* __restrict__ bgf, const float* __restrict__ bgb,
    float* __restrict__ gw, ushort* __restrict__ L16, float* __restrict__ P)
{
    __shared__ ushort Av[64 * 264];
    __shared__ float gsm[64 * 16];
    const int tid = threadIdx.x;
    const int r0 = blockIdx.x * 64, dir = blockIdx.y;
    #pragma unroll
    for (int i = 0; i < 8; ++i) {
        int idx = tid + i * 256; int r = idx >> 5, c = idx & 31;
        *(uint4*)&Av[r * 264 + c * 8] =
            *(const uint4*)(value + (size_t)(r0 + r) * 512 + dir * 256 + c * 8);
    }
    __syncthreads();
    const int w = tid >> 6, l = tid & 63, l15 = l & 15, lk = (l >> 4) * 8;
    const ushort* Wg = WgT + dir * 4096;
    f32x4 acc = {};
    #pragma unroll
    for (int kk = 0; kk < 256; kk += 32) {
        bf16x8 af = *(const bf16x8*)&Av[(w * 16 + l15) * 264 + kk + lk];
        bf16x8 bf = *(const bf16x8*)(Wg + l15 * 256 + kk + lk);
        acc = __builtin_amdgcn_mfma_f32_16x16x32_bf16(af, bf, acc, 0, 0, 0);
    }
    const float bgs = (dir ? bgb : bgf)[l15];
    const int rbase = (l >> 4) * 4;
    const int b = r0 >> 14, t0 = r0 & 16383;
    #pragma unroll
    for (int r = 0; r < 4; ++r) {
        int lr = w * 16 + rbase + r;
        float sv = 1.f / (1.f + __expf(-(acc[r] + bgs)));
        gsm[lr * 16 + l15] = sv;
        gw[((size_t)(dir * NB + b) * SEQ + t0 + lr) * 16 + l15] = sv;
    }
    __syncthreads();
    // local scan: 2 chunks x 128 d-pairs
    const int ci = tid >> 7, dp = tid & 127;
    const int chunk = (t0 >> 5) + ci;
    f32x2 c[16] = {};
    for (int i = 0; i < CL; ++i) {
        int row = dir ? (CL - 1 - i) : i;
        uint vv = *(const uint*)&Av[(ci * 32 + row) * 264 + dp * 2];
        f32x2 v; v.x = bflo(vv); v.y = bfhi(vv);
        float g[16];
        #pragma unroll
        for (int q = 0; q < 4; ++q)
            *(float4*)&g[q * 4] = *(const float4*)&gsm[(ci * 32 + row) * 16 + q * 4];
        #pragma unroll
        for (int s = 0; s < 16; ++s) {
            f32x2 gg; gg.x = g[s]; gg.y = g[s];
            c[s] = v + gg * (c[s] - v);
        }
    }
    // write L16 [d][s] bf16: d0=2dp -> offset dp*32 + s; d1 -> +16
    {
        ushort ub[32];
        #pragma unroll
        for (int s = 0; s < 16; ++s) { ub[s] = f2bf(c[s].x); ub[16 + s] = f2bf(c[s].y); }
        ushort* Lp = L16 + ((size_t)(dir * NB + b) * NC + chunk) * 4096 + dp * 32;
        #pragma unroll
        for (int q = 0; q < 4; ++q)
            *(uint4*)(Lp + q * 8) = *(uint4*)&ub[q * 8];
    }
    if (dp < 16) {
        float p = 1.f;
        for (int t = 0; t < CL; ++t) p *= gsm[(ci * 32 + t) * 16 + dp];
        P[((size_t)(dir * NB + b) * NC + chunk) * 16 + dp] = p;
    }
}

// ---------------- pass B: chunk recurrence on bf16 L, 16-deep dbuf --------------
// block: (dir, b, dgrp 16) -> 128 blocks; thread: dl = tid>>4, s = tid&15
__global__ __launch_bounds__(256, 2) void chunk_scan(
    ushort* __restrict__ L16, const float* __restrict__ P)
{
    const int bid = blockIdx.x;
    const int dir = bid >> 6, b = (bid >> 4) & 3, dgrp = bid & 15;
    const int tid = threadIdx.x;
    const int s = tid & 15;
    const size_t cb = (size_t)(dir * NB + b) * NC;
    ushort* Lb = L16 + cb * 4096 + dgrp * 256 + tid;
    const float* Pb = P + cb * 16 + s;
    float e = 0.f;
    ushort lA[16], lB[16];
    float pA[16], pB[16];

#define LOADB(la, pa, ib) { _Pragma("unroll") \
    for (int j = 0; j < 16; ++j) { \
        int t = (ib) * 16 + j; int k = dir ? (NC - 1 - t) : t; \
        la[j] = Lb[(size_t)k * 4096]; pa[j] = Pb[k * 16]; } }
#define PROCB(la, pa, ib) { _Pragma("unroll") \
    for (int j = 0; j < 16; ++j) { \
        int t = (ib) * 16 + j; int k = dir ? (NC - 1 - t) : t; \
        Lb[(size_t)k * 4096] = f2bf(e); e = pa[j] * e + bf2f(la[j]); } }

    LOADB(lA, pA, 0)
    for (int ib = 0; ib < 32; ib += 2) {
        LOADB(lB, pB, ib + 1)
        PROCB(lA, pA, ib)
        if (ib + 2 < 32) { LOADB(lA, pA, ib + 2) }
        PROCB(lB, pB, ib + 1)
    }
#undef LOADB
#undef PROCB
}

// ---------------- pass C: s-packed local scan + output, write in place ----------
__global__ __launch_bounds__(128, 4) void pass_c(
    ushort* __restrict__ value, const float* __restrict__ gw,
    const ushort* __restrict__ L16, const float* __restrict__ AsT)
{
    const int chunk = blockIdx.x, b = blockIdx.y, dir = blockIdx.z;
    const int tid = threadIdx.x;
    __shared__ float gs[CL * 16];
    const float* gwd = gw + ((size_t)(dir * NB + b) * SEQ + chunk * CL) * 16;
    ((float4*)gs)[tid] = ((const float4*)gwd)[tid];
    __syncthreads();
    ushort* vb = value + ((size_t)b * SEQ + chunk * CL) * 512 + dir * 256 + tid * 2;
    const float* Ad = AsT + dir * 4096 + tid * 32;      // [d0 16s][d1 16s]
    const ushort* Lp = L16 + ((size_t)(dir * NB + b) * NC + chunk) * 4096 + tid * 32;
    f32x2 a0[8], a1[8], c0[8], c1[8];
    #pragma unroll
    for (int sp = 0; sp < 8; ++sp) {
        a0[sp] = *(const f32x2*)(Ad + sp * 2);
        a1[sp] = *(const f32x2*)(Ad + 16 + sp * 2);
        uint u0 = *(const uint*)(Lp + sp * 2);
        uint u1 = *(const uint*)(Lp + 16 + sp * 2);
        c0[sp].x = bflo(u0); c0[sp].y = bfhi(u0);
        c1[sp].x = bflo(u1); c1[sp].y = bfhi(u1);
    }
    uint vbuf[4];
    #pragma unroll
    for (int j = 0; j < 4; ++j) {
        int row = dir ? (CL - 1 - j) : j;
        vbuf[j] = *(const uint*)(vb + (size_t)row * 512);
    }
    for (int i0 = 0; i0 < CL; i0 += 4) {
        uint vcur[4];
        #pragma unroll
        for (int j = 0; j < 4; ++j) vcur[j] = vbuf[j];
        if (i0 + 4 < CL) {
            #pragma unroll
            for (int j = 0; j < 4; ++j) {
                int t = i0 + 4 + j;
                int row = dir ? (CL - 1 - t) : t;
                vbuf[j] = *(const uint*)(vb + (size_t)row * 512);
            }
        }
        #pragma unroll
        for (int j = 0; j < 4; ++j) {
            int t = i0 + j;
            int row = dir ? (CL - 1 - t) : t;
            float v0 = bflo(vcur[j]), v1 = bfhi(vcur[j]);
            f32x2 vd0; vd0.x = v0; vd0.y = v0;
            f32x2 vd1; vd1.x = v1; vd1.y = v1;
            f32x2 o0 = {0.f, 0.f}, o1 = {0.f, 0.f};
            #pragma unroll
            for (int sp = 0; sp < 8; ++sp) {
                f32x2 g = *(const f32x2*)&gs[row * 16 + sp * 2];
                c0[sp] = vd0 + g * (c0[sp] - vd0);
                o0 += (a0[sp] * g) * c0[sp];
                c1[sp] = vd1 + g * (c1[sp] - vd1);
                o1 += (a1[sp] * g) * c1[sp];
            }
            uint outv = (uint)f2bf(o0.x + o0.y) | ((uint)f2bf(o1.x + o1.y) << 16);
            *(uint*)(vb + (size_t)row * 512) = outv;
        }
    }
}

// ---------------- out GEMM: 128x256 tile, K=512, fused LayerNorm ----------------
__global__ __launch_bounds__(512) void gemm_out_ln(
    const ushort* __restrict__ A, const ushort* __restrict__ BT,
    const float* __restrict__ b_out, const float* __restrict__ ln_g,
    const float* __restrict__ ln_b, float* __restrict__ out)
{
    __shared__ ushort Al[128 * 40];
    __shared__ ushort Bl[256 * 40];
    __shared__ float red[2][2][4][64];
    const int tid = threadIdx.x;
    const int m0 = blockIdx.x * 128;
    const int w = tid >> 6, l = tid & 63;
    const int wr = w >> 2, wc = w & 3;
    const int l15 = l & 15, lk = (l >> 4) * 8;
    f32x4 acc[4][4] = {};

    for (int kk = 0; kk < 512; kk += 32) {
        {
            int r = tid >> 2, c = tid & 3;
            *(uint4*)&Al[r * 40 + c * 8] = *(const uint4*)(A + (size_t)(m0 + r) * 512 + kk + c * 8);
        }
        #pragma unroll
        for (int i = 0; i < 2; ++i) {
            int idx = tid + i * 512; int r = idx >> 2, c = idx & 3;
            *(uint4*)&Bl[r * 40 + c * 8] = *(const uint4*)(BT + (size_t)r * 512 + kk + c * 8);
        }
        __syncthreads();
        bf16x8 af[4], bfr[4];
        #pragma unroll
        for (int m = 0; m < 4; ++m) af[m] = *(const bf16x8*)&Al[(wr * 64 + m * 16 + l15) * 40 + lk];
        #pragma unroll
        for (int n = 0; n < 4; ++n) bfr[n] = *(const bf16x8*)&Bl[(wc * 64 + n * 16 + l15) * 40 + lk];
        #pragma unroll
        for (int m = 0; m < 4; ++m)
            #pragma unroll
            for (int n = 0; n < 4; ++n)
                acc[m][n] = __builtin_amdgcn_mfma_f32_16x16x32_bf16(af[m], bfr[n], acc[m][n], 0, 0, 0);
        __syncthreads();
    }
    const int rbase = (l >> 4) * 4;
    float gg[4], bb[4];
    #pragma unroll
    for (int n = 0; n < 4; ++n) {
        int col = wc * 64 + n * 16 + l15;
        float bv = b_out[col];
        gg[n] = ln_g[col]; bb[n] = ln_b[col];
        #pragma unroll
        for (int m = 0; m < 4; ++m)
            #pragma unroll
            for (int r = 0; r < 4; ++r)
                acc[m][n][r] += bv;
    }
    float s1[4][4], s2[4][4];
    #pragma unroll
    for (int m = 0; m < 4; ++m)
        #pragma unroll
        for (int r = 0; r < 4; ++r) {
            float a_ = 0.f, b_ = 0.f;
            #pragma unroll
            for (int n = 0; n < 4; ++n) {
                float v = acc[m][n][r];
                a_ += v; b_ += v * v;
            }
            s1[m][r] = a_; s2[m][r] = b_;
        }
    #pragma unroll
    for (int mask = 1; mask < 16; mask <<= 1)
        #pragma unroll
        for (int m = 0; m < 4; ++m)
            #pragma unroll
            for (int r = 0; r < 4; ++r) {
                s1[m][r] += __shfl_xor(s1[m][r], mask, 64);
                s2[m][r] += __shfl_xor(s2[m][r], mask, 64);
            }
    if (l15 == 0) {
        #pragma unroll
        for (int m = 0; m < 4; ++m)
            #pragma unroll
            for (int r = 0; r < 4; ++r) {
                int row = m * 16 + rbase + r;
                red[0][wr][wc][row] = s1[m][r];
                red[1][wr][wc][row] = s2[m][r];
            }
    }
    __syncthreads();
    #pragma unroll
    for (int m = 0; m < 4; ++m)
        #pragma unroll
        for (int r = 0; r < 4; ++r) {
            int row = m * 16 + rbase + r;
            float t1 = red[0][wr][0][row] + red[0][wr][1][row] + red[0][wr][2][row] + red[0][wr][3][row];
            float t2 = red[1][wr][0][row] + red[1][wr][1][row] + red[1][wr][2][row] + red[1][wr][3][row];
            float mu = t1 * (1.f / 256.f);
            float var = t2 * (1.f / 256.f) - mu * mu;
            float rs = rsqrtf(var + 1e-5f);
            #pragma unroll
            for (int n = 0; n < 4; ++n) {
                int col = wc * 64 + n * 16 + l15;
                out[(size_t)(m0 + wr * 64 + row) * 256 + col] = (acc[m][n][r] - mu) * rs * gg[n] + bb[n];
            }
        }
}

extern "C" void kernel_launch(void* const* d_in, const int* in_sizes, int n_in,
                              void* d_out, int out_size, void* d_ws, size_t ws_size,
                              hipStream_t stream)
{
    const float* x       = (const float*)d_in[0];
    const float* W_fproj = (const float*)d_in[1];
    const float* b_fproj = (const float*)d_in[2];
    const float* A_f     = (const float*)d_in[3];
    const float* W_fgate = (const float*)d_in[4];
    const float* b_fgate = (const float*)d_in[5];
    const float* W_bproj = (const float*)d_in[6];
    const float* b_bproj = (const float*)d_in[7];
    const float* A_b     = (const float*)d_in[8];
    const float* W_bgate = (const float*)d_in[9];
    const float* b_bgate = (const float*)d_in[10];
    const float* W_out   = (const float*)d_in[11];
    const float* b_out   = (const float*)d_in[12];
    const float* ln_g    = (const float*)d_in[13];
    const float* ln_b    = (const float*)d_in[14];

    char* ws = (char*)d_ws;
    ushort* value  = (ushort*)(ws + 0);             // 67108864 B  [row][512]
    float*  gw     = (float*) (ws + 67108864);      //  8388608 B  [dir][b][t][16]
    ushort* L16    = (ushort*)(ws + 75497472);      // 33554432 B  [dir][b][chunk][d][16s] bf16
    float*  P      = (float*) (ws + 109051904);     //   262144 B
    ushort* BTv    = (ushort*)(ws + 109314048);     //   262144 B
    ushort* WoT    = (ushort*)(ws + 109576192);     //   262144 B
    ushort* WgT    = (ushort*)(ws + 109838336);     //    16384 B
    float*  bias_v = (float*) (ws + 109854720);     //     2048 B
    float*  AsT    = (float*) (ws + 109856768);     //    32768 B  [dir][d][s]

    prep_weights<<<1090, 256, 0, stream>>>(W_fproj, W_bproj, W_out, W_fgate, W_bgate,
                                           b_fproj, b_bproj, A_f, A_b,
                                           BTv, WoT, WgT, bias_v, AsT);
    gemm_value<<<dim3(512, 2), 512, 0, stream>>>(x, BTv, bias_v, value);
    gate_scan<<<dim3(1024, 2), 256, 0, stream>>>(value, WgT, b_fgate, b_bgate, gw, L16, P);
    chunk_scan<<<128, 256, 0, stream>>>(L16, P);
    pass_c<<<dim3(NC, NB, 2), 128, 0, stream>>>(value, gw, L16, AsT);
    gemm_out_ln<<<512, 512, 0, stream>>>(value, WoT, b_out, ln_g, ln_b, (float*)d_out);
}